// Round 8
// baseline (4400.632 us; speedup 1.0000x reference)
//
#include <hip/hip_runtime.h>
#include <stdint.h>
#include <stddef.h>

// ---------------------------------------------------------------------------
// LSTM (B=64, T=1024, I=256, H=512) + attention pooling on MI355X (gfx950).
//   k_lstm v12: v8 protocol VERBATIM (sentinel-carrying h at device scope,
//   single-outstanding-probe gather poll, no flags/drains), with ONE
//   geometry change: 64 blocks x 1024 thr (16 waves); 8 chains x 8 blocks
//   (8 batches x 64 units per block, still 4 units per wave).
//   Why: v8/v10/v11 measured that poll PRESSURE, not poll latency, is the
//   wall (probe rate up => FETCH up => slower, monotonically). Gather
//   traffic = 32768/U KB/step (U = units/block): U 32->64 halves coherent
//   request load (1MB -> 512KB/step) and halves lockstep participants per
//   chain (16 -> 8, smaller straggler tail).
//   v9 post-mortem fix: __launch_bounds__(1024, 1) EXPLICIT -> ~512 VGPR/wave
//   available (4 waves/SIMD), so the ~100-VGPR persistent-weight working set
//   fits without spill (v9's bare (1024) defaulted to a 64-VGPR cap ->
//   spills -> regression). No xbuf staging, no scope games, no pipelined
//   probes -- single-variable geometry test.
// ---------------------------------------------------------------------------

typedef _Float16 f16_t;
typedef _Float16 half8 __attribute__((ext_vector_type(8)));
typedef float f32x4 __attribute__((ext_vector_type(4)));

#define MFMA16(a, b, c) __builtin_amdgcn_mfma_f32_16x16x32_f16((a), (b), (c), 0, 0, 0)

static constexpr int BATCH = 64;
static constexpr int TLEN = 1024;
static constexpr int IDIM = 256;
static constexpr int HDIM = 512;

__device__ __forceinline__ float sigf(float x) { return 1.f / (1.f + __expf(-x)); }
__device__ __forceinline__ float tanh_fast(float x) {
  float e = __expf(2.f * fabsf(x));
  float t = 1.f - 2.f / (e + 1.f);
  return copysignf(t, x);
}
__device__ __forceinline__ half8 load_cvt8(const float* p) {
  f32x4 a = *(const f32x4*)p;
  f32x4 b = *(const f32x4*)(p + 4);
  half8 r;
#pragma unroll
  for (int j = 0; j < 4; ++j) { r[j] = (f16_t)a[j]; r[4 + j] = (f16_t)b[j]; }
  return r;
}

// device-scope (sc0 sc1) 16B load with completion wait: IC is the coherence
// point across XCDs -- the path v4/v6/v8 validated.
__device__ __forceinline__ f32x4 ld16_llc(const f16_t* p) {
  f32x4 v;
  asm volatile("global_load_dwordx4 %0, %1, off sc0 sc1\n\ts_waitcnt vmcnt(0)"
               : "=&v"(v) : "v"(p) : "memory");
  return v;
}

// true iff none of the 8 f16 lanes equals the 0xFEFE sentinel
__device__ __forceinline__ bool clean16(const f32x4& v) {
  const unsigned* u = (const unsigned*)&v;
  bool ok = true;
#pragma unroll
  for (int i = 0; i < 4; ++i) {
    ok = ok && ((u[i] & 0xFFFFu) != 0xFEFEu);
    ok = ok && ((u[i] >> 16) != 0xFEFEu);
  }
  return ok;
}

// ---------------------------------------------------------------------------
__global__ __launch_bounds__(256) void k_prep_x(const float* __restrict__ x,
                                                f16_t* __restrict__ xT) {
  __shared__ f16_t sx[64][IDIM + 8];
  const int t = blockIdx.x;
  const int tid = threadIdx.x;
#pragma unroll 4
  for (int b = 0; b < 64; ++b)
    sx[b][tid] = (f16_t)x[((size_t)b * TLEN + t) * IDIM + tid];
  __syncthreads();
#pragma unroll
  for (int it = 0; it < 8; ++it) {
    const int c = it * 256 + tid;      // c = kk4*64 + b
    const int b = c & 63, kk4 = c >> 6;
    half8 v = *(const half8*)&sx[b][kk4 * 8];
    *(half8*)(xT + (((size_t)t * 32 + kk4) * 64 + b) * 8) = v;
  }
}

__global__ __launch_bounds__(256) void k_prep_w(const float* __restrict__ Wa,
                                                f16_t* __restrict__ WaT) {
  const int id = blockIdx.x * 256 + threadIdx.x;   // 0..32767
  const int n = id & 511, kk4 = id >> 9;
  half8 v = load_cvt8(&Wa[(size_t)n * HDIM + kk4 * 8]);
  *(half8*)(WaT + ((size_t)kk4 * HDIM + n) * 8) = v;
}

// ---------------------------------------------------------------------------
// Recurrence. Roles static: bg = bid&7 (chain), ug = bid>>3 (0..7).
// Batches bg*8..+7, units ug*64..+63. Wave w (0..15): units u0=ug*64+w*4..+3.
// MFMA M rows [unit][gate]; N lanes col 0..15 carry batch (col&7) (cols
// 8..15 duplicate, discarded on store). h(t) stores into sentinel-poisoned
// hs are self-announcing; gather = poll (waves 0..7; waves 8..15 wait at
// the barrier).
// ---------------------------------------------------------------------------
__global__ __launch_bounds__(1024, 1) void k_lstm(
    const float* __restrict__ Whh, const float* __restrict__ Wih,
    const float* __restrict__ bih, const float* __restrict__ bhh,
    const f16_t* __restrict__ xT, f16_t* __restrict__ hs) {
  const int tid = threadIdx.x;
  const int w = tid >> 6;                  // wave 0..15
  const int L = tid & 63;
  const int q = L >> 4, col = L & 15;
  const int bid = blockIdx.x;              // 0..63
  const int bg = bid & 7;                  // chain / batch group
  const int ug = bid >> 3;                 // 0..7 unit group

  const int u0 = ug * 64 + w * 4;
  const int b8 = col & 7;                  // chain-local batch
  const int bglob = bg * 8 + b8;           // global batch
  const int myu = u0 + q;

  __shared__ __align__(16) f16_t hin[8][520];   // h(t-1): 1040B stride
  __shared__ __align__(16) f16_t hout[8][72];   // block's h(t): 144B stride

  // Persistent A-fragments: A[m=col][k=q*8+j]; m = unit_local*4 + gate.
  const int arow = (col & 3) * HDIM + u0 + (col >> 2);
  half8 wAh[16], wAx[8];
#pragma unroll
  for (int kk = 0; kk < 16; ++kk)
    wAh[kk] = load_cvt8(&Whh[(size_t)arow * HDIM + kk * 32 + q * 8]);
#pragma unroll
  for (int kk = 0; kk < 8; ++kk)
    wAx[kk] = load_cvt8(&Wih[(size_t)arow * IDIM + kk * 32 + q * 8]);

  float pb[4];
#pragma unroll
  for (int r = 0; r < 4; ++r) pb[r] = bih[r * HDIM + myu] + bhh[r * HDIM + myu];

  auto xgemm = [&](int t) {
    f32x4 a = {0.f, 0.f, 0.f, 0.f};
#pragma unroll
    for (int kk = 0; kk < 8; ++kk) {
      half8 bf = *(const half8*)(xT +
          (((size_t)(t - 1) * 32 + kk * 4 + q) * 64 + bglob) * 8);
      a = MFMA16(wAx[kk], bf, a);
    }
    return a;
  };

  float c = 0.f;
  f32x4 xacc = xgemm(1);
  for (int t = 1; t <= TLEN; ++t) {
    // ---- gather h(t-1) with data-embedded readiness: wave w (<8) polls the
    //      full 512-unit row of batch bg*8+w; only stale lanes re-fetch ----
    if (w < 8) {
      const f16_t* src = hs + ((size_t)(t - 1) * BATCH + bg * 8 + w) * HDIM
                         + L * 8;          // 16B per lane, 1KB per wave
      f32x4 v = ld16_llc(src);
      int guard = 0;
      for (;;) {
        const bool ok = clean16(v);
        if (__ballot(ok) == ~0ull) break;
        if (!ok) v = ld16_llc(src);        // exec-masked retry
        if (++guard > (1 << 22)) break;    // fail loud, not hung
      }
      *(f32x4*)&hin[w][L * 8] = v;
    }
    __syncthreads();                       // hin complete

    // ---- MFMA: B-frags broadcast-read from LDS, dual accumulators ----
    f32x4 a0 = xacc, a1 = {0.f, 0.f, 0.f, 0.f};
#pragma unroll
    for (int kk = 0; kk < 16; kk += 2) {
      half8 b0 = *(const half8*)&hin[b8][kk * 32 + q * 8];
      half8 b1 = *(const half8*)&hin[b8][(kk + 1) * 32 + q * 8];
      a0 = MFMA16(wAh[kk], b0, a0);
      a1 = MFMA16(wAh[kk + 1], b1, a1);
    }
    const f32x4 acc = a0 + a1;

    const float ig = sigf(acc[0] + pb[0]);
    const float fg = sigf(acc[1] + pb[1]);
    const float gg = tanh_fast(acc[2] + pb[2]);
    const float og = sigf(acc[3] + pb[3]);
    c = fg * c + ig * gg;
    if (col < 8) hout[col][w * 4 + q] = (f16_t)(og * tanh_fast(c));

    __syncthreads();                       // hout ready, hin consumed

    // ---- wave 0: 8 batches x 128B coalesced stores; no drain, no flag ----
    if (w == 0) {
      const int sb = L >> 3, ck = L & 7;   // batch, 16B chunk
      f32x4 v = *(const f32x4*)&hout[sb][ck * 8];
      f16_t* dst = hs + ((size_t)t * BATCH + bg * 8 + sb) * HDIM
                   + ug * 64 + ck * 8;
      asm volatile("global_store_dwordx4 %0, %1, off sc0 sc1"
                   :: "v"(dst), "v"(v) : "memory");
    }

    // x-projection for the NEXT step: overlaps other blocks' compute
    if (t < TLEN) xacc = xgemm(t + 1);
  }
}

// ---------------------------------------------------------------------------
__global__ __launch_bounds__(256) void k_attn(
    const f16_t* __restrict__ hse, const f16_t* __restrict__ WaT,
    const float* __restrict__ battn, f16_t* __restrict__ E) {
  const int w = threadIdx.x >> 6;
  const int L = threadIdx.x & 63;
  const int q = L >> 4, col = L & 15;
  const int m0 = blockIdx.x * 64 + w * 16;   // r rows (r = t*64+b)
  const int n0 = blockIdx.y * 64;            // h cols

  f32x4 acc[4];
#pragma unroll
  for (int nt = 0; nt < 4; ++nt) acc[nt] = {0.f, 0.f, 0.f, 0.f};

#pragma unroll 4
  for (int kk = 0; kk < 16; ++kk) {          // K = 512
    half8 af = *(const half8*)(hse + (size_t)(m0 + col) * HDIM + kk * 32 + q * 8);
#pragma unroll
    for (int nt = 0; nt < 4; ++nt) {
      half8 bf = *(const half8*)(WaT +
          ((size_t)(kk * 4 + q) * HDIM + n0 + nt * 16 + col) * 8);
      acc[nt] = MFMA16(af, bf, acc[nt]);
    }
  }
#pragma unroll
  for (int nt = 0; nt < 4; ++nt) {
    const int h = n0 + nt * 16 + col;
    const float bias = battn[h];
#pragma unroll
    for (int r = 0; r < 4; ++r) {
      const int m = m0 + q * 4 + r;
      E[(size_t)m * HDIM + h] = (f16_t)__expf(tanh_fast(acc[nt][r] + bias));
    }
  }
}

__global__ __launch_bounds__(256) void k_pool(
    const f16_t* __restrict__ E, const f16_t* __restrict__ hse,
    float* __restrict__ pnum, float* __restrict__ pden) {
  const int b = blockIdx.x;
  const int hc = blockIdx.y;
  const int tc = blockIdx.z;
  const int h = hc * 256 + threadIdx.x;
  float num = 0.f, den = 0.f;
#pragma unroll 4
  for (int tt = 0; tt < 256; ++tt) {
    const int t = tc * 256 + tt;
    const size_t idx = ((size_t)t * BATCH + b) * HDIM + h;
    const float e = (float)E[idx];
    const float hv = (float)hse[idx];
    den += e;
    num += e * hv;
  }
  const size_t pi = ((size_t)tc * BATCH + b) * HDIM + h;
  pnum[pi] = num;
  pden[pi] = den;
}

__global__ __launch_bounds__(256) void k_final(
    const float* __restrict__ pnum, const float* __restrict__ pden,
    float* __restrict__ out) {
  const int i = blockIdx.x * 256 + threadIdx.x;   // b*512+h
  float n = 0.f, d = 0.f;
#pragma unroll
  for (int z = 0; z < 4; ++z) {
    n += pnum[(size_t)z * 32768 + i];
    d += pden[(size_t)z * 32768 + i];
  }
  out[i] = n / d;
}

// ---------------------------------------------------------------------------
extern "C" void kernel_launch(void* const* d_in, const int* in_sizes, int n_in,
                              void* d_out, int out_size, void* d_ws, size_t ws_size,
                              hipStream_t stream) {
  const float* x   = (const float*)d_in[0];
  const float* Wih = (const float*)d_in[1];
  const float* Whh = (const float*)d_in[2];
  const float* bih = (const float*)d_in[3];
  const float* bhh = (const float*)d_in[4];
  const float* Wat = (const float*)d_in[5];
  const float* bat = (const float*)d_in[6];
  float* out = (float*)d_out;

  char* ws = (char*)d_ws;
  const size_t REGA_BYTES = (size_t)64 * 1024 * 1024;                        // xT then E
  const size_t HS_BYTES = (size_t)(TLEN + 1) * BATCH * HDIM * sizeof(f16_t); // 67.2MB
  const size_t WAT_BYTES = (size_t)64 * HDIM * 8 * sizeof(f16_t);            // 512KB
  const size_t P_BYTES = (size_t)4 * BATCH * HDIM * sizeof(float);           // 512KB

  f16_t* xT = (f16_t*)ws;
  f16_t* E  = (f16_t*)ws;
  f16_t* hs = (f16_t*)(ws + REGA_BYTES);
  f16_t* WaT = (f16_t*)(ws + REGA_BYTES + HS_BYTES);
  float* pnum = (float*)(ws + REGA_BYTES + HS_BYTES + WAT_BYTES);
  float* pden = (float*)(ws + REGA_BYTES + HS_BYTES + WAT_BYTES + P_BYTES);

  const size_t SLAB = (size_t)BATCH * HDIM * sizeof(f16_t);   // 64KB
  // slab 0 = h(0) = zeros; slabs 1..1024 = 0xFEFE sentinel (re-poison every
  // launch: the sentinel IS the readiness protocol).
  hipMemsetAsync(hs, 0, SLAB, stream);
  hipMemsetAsync((char*)hs + SLAB, 0xFE, (size_t)TLEN * SLAB, stream);

  k_prep_x<<<dim3(TLEN), 256, 0, stream>>>(x, xT);
  k_prep_w<<<dim3(128), 256, 0, stream>>>(Wat, WaT);
  k_lstm<<<dim3(64), 1024, 0, stream>>>(Whh, Wih, bih, bhh, xT, hs);

  const f16_t* hse = hs + (size_t)BATCH * HDIM;   // slab 1 == reference hs[0]
  k_attn<<<dim3(1024, 8), 256, 0, stream>>>(hse, WaT, bat, E);
  k_pool<<<dim3(64, 2, 4), 256, 0, stream>>>(E, hse, pnum, pden);
  k_final<<<dim3(128), 256, 0, stream>>>(pnum, pden, out);
}

// Round 9
// 3269.318 us; speedup vs baseline: 1.3460x; 1.3460x over previous
//
#include <hip/hip_runtime.h>
#include <stdint.h>
#include <stddef.h>

// ---------------------------------------------------------------------------
// LSTM (B=64, T=1024, I=256, H=512) + attention pooling on MI355X (gfx950).
//   k_lstm v13: U=64 geometry inside the PROVEN 512-thread/8-wave skeleton.
//   64 blocks x 512 thr; 8 chains x 8 blocks (8 batches x 64 units/block);
//   each wave owns 8 units = TWO M-tiles (wAh0/1[16], wAx0/1[8], ~192 VGPR
//   of persistent weights; budget 256 under launch_bounds(512,2)).
//   v12 post-mortem: hipcc force-caps 1024-thr blocks at 64 VGPR (measured
//   twice, v9+v12) -> weight spills -> scratch reloads each step -> 4us/step.
//   1024-thr blocks are unusable; U=64 gets its clean test here instead.
//   Protocol = v8 VERBATIM: sentinel-carrying h (slabs poisoned 0xFEFE; h
//   finite so stored f16 never equals sentinel); consumers gather h(t-1)
//   directly at device scope (sc0 sc1) retrying stale lanes (poll == gather);
//   producers store with no drain/flag. Why U=64: poll PRESSURE is the
//   measured wall (v10/v11: more probes -> more FETCH -> slower). Gather
//   traffic = (512/U)*64KB/step: U 32->64 halves it (1MB -> 512KB) and
//   halves lockstep producers per chain (16 -> 8, smaller straggler tail).
//   B-fragments are shared by both M-tiles: the 2nd tile costs only MFMAs
//   (5% utilized), zero extra LDS/global traffic.
// ---------------------------------------------------------------------------

typedef _Float16 f16_t;
typedef _Float16 half8 __attribute__((ext_vector_type(8)));
typedef float f32x4 __attribute__((ext_vector_type(4)));

#define MFMA16(a, b, c) __builtin_amdgcn_mfma_f32_16x16x32_f16((a), (b), (c), 0, 0, 0)

static constexpr int BATCH = 64;
static constexpr int TLEN = 1024;
static constexpr int IDIM = 256;
static constexpr int HDIM = 512;

__device__ __forceinline__ float sigf(float x) { return 1.f / (1.f + __expf(-x)); }
__device__ __forceinline__ float tanh_fast(float x) {
  float e = __expf(2.f * fabsf(x));
  float t = 1.f - 2.f / (e + 1.f);
  return copysignf(t, x);
}
__device__ __forceinline__ half8 load_cvt8(const float* p) {
  f32x4 a = *(const f32x4*)p;
  f32x4 b = *(const f32x4*)(p + 4);
  half8 r;
#pragma unroll
  for (int j = 0; j < 4; ++j) { r[j] = (f16_t)a[j]; r[4 + j] = (f16_t)b[j]; }
  return r;
}

// device-scope (sc0 sc1) 16B load with completion wait: IC is the coherence
// point across XCDs -- the path v4/v6/v8 validated.
__device__ __forceinline__ f32x4 ld16_llc(const f16_t* p) {
  f32x4 v;
  asm volatile("global_load_dwordx4 %0, %1, off sc0 sc1\n\ts_waitcnt vmcnt(0)"
               : "=&v"(v) : "v"(p) : "memory");
  return v;
}

// true iff none of the 8 f16 lanes equals the 0xFEFE sentinel
__device__ __forceinline__ bool clean16(const f32x4& v) {
  const unsigned* u = (const unsigned*)&v;
  bool ok = true;
#pragma unroll
  for (int i = 0; i < 4; ++i) {
    ok = ok && ((u[i] & 0xFFFFu) != 0xFEFEu);
    ok = ok && ((u[i] >> 16) != 0xFEFEu);
  }
  return ok;
}

// ---------------------------------------------------------------------------
__global__ __launch_bounds__(256) void k_prep_x(const float* __restrict__ x,
                                                f16_t* __restrict__ xT) {
  __shared__ f16_t sx[64][IDIM + 8];
  const int t = blockIdx.x;
  const int tid = threadIdx.x;
#pragma unroll 4
  for (int b = 0; b < 64; ++b)
    sx[b][tid] = (f16_t)x[((size_t)b * TLEN + t) * IDIM + tid];
  __syncthreads();
#pragma unroll
  for (int it = 0; it < 8; ++it) {
    const int c = it * 256 + tid;      // c = kk4*64 + b
    const int b = c & 63, kk4 = c >> 6;
    half8 v = *(const half8*)&sx[b][kk4 * 8];
    *(half8*)(xT + (((size_t)t * 32 + kk4) * 64 + b) * 8) = v;
  }
}

__global__ __launch_bounds__(256) void k_prep_w(const float* __restrict__ Wa,
                                                f16_t* __restrict__ WaT) {
  const int id = blockIdx.x * 256 + threadIdx.x;   // 0..32767
  const int n = id & 511, kk4 = id >> 9;
  half8 v = load_cvt8(&Wa[(size_t)n * HDIM + kk4 * 8]);
  *(half8*)(WaT + ((size_t)kk4 * HDIM + n) * 8) = v;
}

// ---------------------------------------------------------------------------
// Recurrence. Roles static: bg = bid&7 (chain), ug = bid>>3 (0..7).
// Batches bg*8..+7, units ug*64..+63. Wave w (0..7): units u0=ug*64+w*8..+7,
// split as tile0 = u0..u0+3, tile1 = u0+4..u0+7. MFMA M rows [unit][gate];
// N lanes col 0..15 carry batch (col&7) (cols 8..15 duplicate, discarded).
// h(t) stores into sentinel-poisoned hs are self-announcing; gather = poll
// (all 8 waves, one batch-row each).
// ---------------------------------------------------------------------------
__global__ __launch_bounds__(512, 2) void k_lstm(
    const float* __restrict__ Whh, const float* __restrict__ Wih,
    const float* __restrict__ bih, const float* __restrict__ bhh,
    const f16_t* __restrict__ xT, f16_t* __restrict__ hs) {
  const int tid = threadIdx.x;
  const int w = tid >> 6;                  // wave 0..7
  const int L = tid & 63;
  const int q = L >> 4, col = L & 15;
  const int bid = blockIdx.x;              // 0..63
  const int bg = bid & 7;                  // chain / batch group
  const int ug = bid >> 3;                 // 0..7 unit group

  const int u0 = ug * 64 + w * 8;          // 8 units per wave
  const int b8 = col & 7;                  // chain-local batch
  const int bglob = bg * 8 + b8;           // global batch
  const int myu0 = u0 + q;                 // tile0 unit for this lane
  const int myu1 = u0 + 4 + q;             // tile1 unit

  __shared__ __align__(16) f16_t hin[8][520];   // h(t-1): 1040B stride
  __shared__ __align__(16) f16_t hout[8][72];   // block's h(t): 144B stride

  // Persistent A-fragments: A[m=col][k=q*8+j]; m = unit_local*4 + gate.
  const int arow0 = (col & 3) * HDIM + u0 + (col >> 2);
  const int arow1 = arow0 + 4;
  half8 wAh0[16], wAh1[16], wAx0[8], wAx1[8];
#pragma unroll
  for (int kk = 0; kk < 16; ++kk) {
    wAh0[kk] = load_cvt8(&Whh[(size_t)arow0 * HDIM + kk * 32 + q * 8]);
    wAh1[kk] = load_cvt8(&Whh[(size_t)arow1 * HDIM + kk * 32 + q * 8]);
  }
#pragma unroll
  for (int kk = 0; kk < 8; ++kk) {
    wAx0[kk] = load_cvt8(&Wih[(size_t)arow0 * IDIM + kk * 32 + q * 8]);
    wAx1[kk] = load_cvt8(&Wih[(size_t)arow1 * IDIM + kk * 32 + q * 8]);
  }

  float pb0[4], pb1[4];
#pragma unroll
  for (int r = 0; r < 4; ++r) {
    pb0[r] = bih[r * HDIM + myu0] + bhh[r * HDIM + myu0];
    pb1[r] = bih[r * HDIM + myu1] + bhh[r * HDIM + myu1];
  }

  auto xgemm = [&](int t, f32x4& x0, f32x4& x1) {
    x0 = {0.f, 0.f, 0.f, 0.f};
    x1 = {0.f, 0.f, 0.f, 0.f};
#pragma unroll
    for (int kk = 0; kk < 8; ++kk) {
      half8 bf = *(const half8*)(xT +
          (((size_t)(t - 1) * 32 + kk * 4 + q) * 64 + bglob) * 8);
      x0 = MFMA16(wAx0[kk], bf, x0);
      x1 = MFMA16(wAx1[kk], bf, x1);
    }
  };

  float c0 = 0.f, c1 = 0.f;
  f32x4 xacc0, xacc1;
  xgemm(1, xacc0, xacc1);
  for (int t = 1; t <= TLEN; ++t) {
    // ---- gather h(t-1) with data-embedded readiness: wave w polls the full
    //      512-unit row of batch bg*8+w; only stale lanes re-fetch ----
    {
      const f16_t* src = hs + ((size_t)(t - 1) * BATCH + bg * 8 + w) * HDIM
                         + L * 8;          // 16B per lane, 1KB per wave
      f32x4 v = ld16_llc(src);
      int guard = 0;
      for (;;) {
        const bool ok = clean16(v);
        if (__ballot(ok) == ~0ull) break;
        if (!ok) v = ld16_llc(src);        // exec-masked retry
        if (++guard > (1 << 22)) break;    // fail loud, not hung
      }
      *(f32x4*)&hin[w][L * 8] = v;
    }
    __syncthreads();                       // hin complete

    // ---- MFMA: shared B-frags from LDS feed BOTH M-tiles ----
    f32x4 a0 = xacc0, a1 = {0.f, 0.f, 0.f, 0.f};
    f32x4 a2 = xacc1, a3 = {0.f, 0.f, 0.f, 0.f};
#pragma unroll
    for (int kk = 0; kk < 16; kk += 2) {
      half8 b0 = *(const half8*)&hin[b8][kk * 32 + q * 8];
      half8 b1 = *(const half8*)&hin[b8][(kk + 1) * 32 + q * 8];
      a0 = MFMA16(wAh0[kk], b0, a0);
      a2 = MFMA16(wAh1[kk], b0, a2);
      a1 = MFMA16(wAh0[kk + 1], b1, a1);
      a3 = MFMA16(wAh1[kk + 1], b1, a3);
    }
    const f32x4 acc0 = a0 + a1;
    const f32x4 acc1 = a2 + a3;

    {
      const float ig = sigf(acc0[0] + pb0[0]);
      const float fg = sigf(acc0[1] + pb0[1]);
      const float gg = tanh_fast(acc0[2] + pb0[2]);
      const float og = sigf(acc0[3] + pb0[3]);
      c0 = fg * c0 + ig * gg;
      if (col < 8) hout[col][w * 8 + q] = (f16_t)(og * tanh_fast(c0));
    }
    {
      const float ig = sigf(acc1[0] + pb1[0]);
      const float fg = sigf(acc1[1] + pb1[1]);
      const float gg = tanh_fast(acc1[2] + pb1[2]);
      const float og = sigf(acc1[3] + pb1[3]);
      c1 = fg * c1 + ig * gg;
      if (col < 8) hout[col][w * 8 + 4 + q] = (f16_t)(og * tanh_fast(c1));
    }

    __syncthreads();                       // hout ready, hin consumed

    // ---- wave 0: 8 batches x 128B coalesced stores; no drain, no flag ----
    if (w == 0) {
      const int sb = L >> 3, ck = L & 7;   // batch, 16B chunk
      f32x4 v = *(const f32x4*)&hout[sb][ck * 8];
      f16_t* dst = hs + ((size_t)t * BATCH + bg * 8 + sb) * HDIM
                   + ug * 64 + ck * 8;
      asm volatile("global_store_dwordx4 %0, %1, off sc0 sc1"
                   :: "v"(dst), "v"(v) : "memory");
    }

    // x-projection for the NEXT step: overlaps other blocks' compute
    if (t < TLEN) xgemm(t + 1, xacc0, xacc1);
  }
}

// ---------------------------------------------------------------------------
__global__ __launch_bounds__(256) void k_attn(
    const f16_t* __restrict__ hse, const f16_t* __restrict__ WaT,
    const float* __restrict__ battn, f16_t* __restrict__ E) {
  const int w = threadIdx.x >> 6;
  const int L = threadIdx.x & 63;
  const int q = L >> 4, col = L & 15;
  const int m0 = blockIdx.x * 64 + w * 16;   // r rows (r = t*64+b)
  const int n0 = blockIdx.y * 64;            // h cols

  f32x4 acc[4];
#pragma unroll
  for (int nt = 0; nt < 4; ++nt) acc[nt] = {0.f, 0.f, 0.f, 0.f};

#pragma unroll 4
  for (int kk = 0; kk < 16; ++kk) {          // K = 512
    half8 af = *(const half8*)(hse + (size_t)(m0 + col) * HDIM + kk * 32 + q * 8);
#pragma unroll
    for (int nt = 0; nt < 4; ++nt) {
      half8 bf = *(const half8*)(WaT +
          ((size_t)(kk * 4 + q) * HDIM + n0 + nt * 16 + col) * 8);
      acc[nt] = MFMA16(af, bf, acc[nt]);
    }
  }
#pragma unroll
  for (int nt = 0; nt < 4; ++nt) {
    const int h = n0 + nt * 16 + col;
    const float bias = battn[h];
#pragma unroll
    for (int r = 0; r < 4; ++r) {
      const int m = m0 + q * 4 + r;
      E[(size_t)m * HDIM + h] = (f16_t)__expf(tanh_fast(acc[nt][r] + bias));
    }
  }
}

__global__ __launch_bounds__(256) void k_pool(
    const f16_t* __restrict__ E, const f16_t* __restrict__ hse,
    float* __restrict__ pnum, float* __restrict__ pden) {
  const int b = blockIdx.x;
  const int hc = blockIdx.y;
  const int tc = blockIdx.z;
  const int h = hc * 256 + threadIdx.x;
  float num = 0.f, den = 0.f;
#pragma unroll 4
  for (int tt = 0; tt < 256; ++tt) {
    const int t = tc * 256 + tt;
    const size_t idx = ((size_t)t * BATCH + b) * HDIM + h;
    const float e = (float)E[idx];
    const float hv = (float)hse[idx];
    den += e;
    num += e * hv;
  }
  const size_t pi = ((size_t)tc * BATCH + b) * HDIM + h;
  pnum[pi] = num;
  pden[pi] = den;
}

__global__ __launch_bounds__(256) void k_final(
    const float* __restrict__ pnum, const float* __restrict__ pden,
    float* __restrict__ out) {
  const int i = blockIdx.x * 256 + threadIdx.x;   // b*512+h
  float n = 0.f, d = 0.f;
#pragma unroll
  for (int z = 0; z < 4; ++z) {
    n += pnum[(size_t)z * 32768 + i];
    d += pden[(size_t)z * 32768 + i];
  }
  out[i] = n / d;
}

// ---------------------------------------------------------------------------
extern "C" void kernel_launch(void* const* d_in, const int* in_sizes, int n_in,
                              void* d_out, int out_size, void* d_ws, size_t ws_size,
                              hipStream_t stream) {
  const float* x   = (const float*)d_in[0];
  const float* Wih = (const float*)d_in[1];
  const float* Whh = (const float*)d_in[2];
  const float* bih = (const float*)d_in[3];
  const float* bhh = (const float*)d_in[4];
  const float* Wat = (const float*)d_in[5];
  const float* bat = (const float*)d_in[6];
  float* out = (float*)d_out;

  char* ws = (char*)d_ws;
  const size_t REGA_BYTES = (size_t)64 * 1024 * 1024;                        // xT then E
  const size_t HS_BYTES = (size_t)(TLEN + 1) * BATCH * HDIM * sizeof(f16_t); // 67.2MB
  const size_t WAT_BYTES = (size_t)64 * HDIM * 8 * sizeof(f16_t);            // 512KB
  const size_t P_BYTES = (size_t)4 * BATCH * HDIM * sizeof(float);           // 512KB

  f16_t* xT = (f16_t*)ws;
  f16_t* E  = (f16_t*)ws;
  f16_t* hs = (f16_t*)(ws + REGA_BYTES);
  f16_t* WaT = (f16_t*)(ws + REGA_BYTES + HS_BYTES);
  float* pnum = (float*)(ws + REGA_BYTES + HS_BYTES + WAT_BYTES);
  float* pden = (float*)(ws + REGA_BYTES + HS_BYTES + WAT_BYTES + P_BYTES);

  const size_t SLAB = (size_t)BATCH * HDIM * sizeof(f16_t);   // 64KB
  // slab 0 = h(0) = zeros; slabs 1..1024 = 0xFEFE sentinel (re-poison every
  // launch: the sentinel IS the readiness protocol).
  hipMemsetAsync(hs, 0, SLAB, stream);
  hipMemsetAsync((char*)hs + SLAB, 0xFE, (size_t)TLEN * SLAB, stream);

  k_prep_x<<<dim3(TLEN), 256, 0, stream>>>(x, xT);
  k_prep_w<<<dim3(128), 256, 0, stream>>>(Wat, WaT);
  k_lstm<<<dim3(64), 512, 0, stream>>>(Whh, Wih, bih, bhh, xT, hs);

  const f16_t* hse = hs + (size_t)BATCH * HDIM;   // slab 1 == reference hs[0]
  k_attn<<<dim3(1024, 8), 256, 0, stream>>>(hse, WaT, bat, E);
  k_pool<<<dim3(64, 2, 4), 256, 0, stream>>>(E, hse, pnum, pden);
  k_final<<<dim3(128), 256, 0, stream>>>(pnum, pden, out);
}

// Round 10
// 3266.058 us; speedup vs baseline: 1.3474x; 1.0010x over previous
//
#include <hip/hip_runtime.h>
#include <stdint.h>
#include <stddef.h>

// ---------------------------------------------------------------------------
// LSTM (B=64, T=1024, I=256, H=512) + attention pooling on MI355X (gfx950).
//   k_lstm v14: v13 BIT-FOR-BIT except __launch_bounds__(512, 1).
//   Empirical launch-bounds finding (v8/v13): with 512-thr blocks, arg2=2
//   compiles to a 4-waves/SIMD floor -> hard 128-VGPR cap; v13's two-M-tile
//   working set (~230 VGPR: 48 half8 weight frags = 192 + infra) spilled ->
//   per-step scratch reloads -> regression. arg2=1 -> 2 waves/SIMD floor
//   (one 8-wave block/CU) -> 256-VGPR budget -> fits sans spill. Occupancy
//   is unchanged in practice (64 blocks on 256 CUs = 1 block/CU anyway;
//   kernel is latency-bound).
//   Geometry: 64 blocks x 512 thr; 8 chains x 8 blocks (8 batches x 64
//   units/block); each wave owns 8 units = TWO M-tiles sharing B-fragments
//   (2nd tile costs only MFMAs, zero extra LDS/global traffic).
//   Why U=64: poll PRESSURE is the measured wall (v10/v11: more probes ->
//   more FETCH -> slower). Gather traffic = 32768/U KB/step: U 32->64
//   halves it (1MB -> 512KB) and halves lockstep producers per chain
//   (16 -> 8, smaller straggler tail).
//   Protocol = v8 VERBATIM: sentinel-carrying h (slabs poisoned 0xFEFE; h
//   finite so stored f16 never equals sentinel); consumers gather h(t-1) at
//   device scope (sc0 sc1) retrying stale lanes (poll == gather); producers
//   store with no drain/flag.
// ---------------------------------------------------------------------------

typedef _Float16 f16_t;
typedef _Float16 half8 __attribute__((ext_vector_type(8)));
typedef float f32x4 __attribute__((ext_vector_type(4)));

#define MFMA16(a, b, c) __builtin_amdgcn_mfma_f32_16x16x32_f16((a), (b), (c), 0, 0, 0)

static constexpr int BATCH = 64;
static constexpr int TLEN = 1024;
static constexpr int IDIM = 256;
static constexpr int HDIM = 512;

__device__ __forceinline__ float sigf(float x) { return 1.f / (1.f + __expf(-x)); }
__device__ __forceinline__ float tanh_fast(float x) {
  float e = __expf(2.f * fabsf(x));
  float t = 1.f - 2.f / (e + 1.f);
  return copysignf(t, x);
}
__device__ __forceinline__ half8 load_cvt8(const float* p) {
  f32x4 a = *(const f32x4*)p;
  f32x4 b = *(const f32x4*)(p + 4);
  half8 r;
#pragma unroll
  for (int j = 0; j < 4; ++j) { r[j] = (f16_t)a[j]; r[4 + j] = (f16_t)b[j]; }
  return r;
}

// device-scope (sc0 sc1) 16B load with completion wait: IC is the coherence
// point across XCDs -- the path v4/v6/v8 validated.
__device__ __forceinline__ f32x4 ld16_llc(const f16_t* p) {
  f32x4 v;
  asm volatile("global_load_dwordx4 %0, %1, off sc0 sc1\n\ts_waitcnt vmcnt(0)"
               : "=&v"(v) : "v"(p) : "memory");
  return v;
}

// true iff none of the 8 f16 lanes equals the 0xFEFE sentinel
__device__ __forceinline__ bool clean16(const f32x4& v) {
  const unsigned* u = (const unsigned*)&v;
  bool ok = true;
#pragma unroll
  for (int i = 0; i < 4; ++i) {
    ok = ok && ((u[i] & 0xFFFFu) != 0xFEFEu);
    ok = ok && ((u[i] >> 16) != 0xFEFEu);
  }
  return ok;
}

// ---------------------------------------------------------------------------
__global__ __launch_bounds__(256) void k_prep_x(const float* __restrict__ x,
                                                f16_t* __restrict__ xT) {
  __shared__ f16_t sx[64][IDIM + 8];
  const int t = blockIdx.x;
  const int tid = threadIdx.x;
#pragma unroll 4
  for (int b = 0; b < 64; ++b)
    sx[b][tid] = (f16_t)x[((size_t)b * TLEN + t) * IDIM + tid];
  __syncthreads();
#pragma unroll
  for (int it = 0; it < 8; ++it) {
    const int c = it * 256 + tid;      // c = kk4*64 + b
    const int b = c & 63, kk4 = c >> 6;
    half8 v = *(const half8*)&sx[b][kk4 * 8];
    *(half8*)(xT + (((size_t)t * 32 + kk4) * 64 + b) * 8) = v;
  }
}

__global__ __launch_bounds__(256) void k_prep_w(const float* __restrict__ Wa,
                                                f16_t* __restrict__ WaT) {
  const int id = blockIdx.x * 256 + threadIdx.x;   // 0..32767
  const int n = id & 511, kk4 = id >> 9;
  half8 v = load_cvt8(&Wa[(size_t)n * HDIM + kk4 * 8]);
  *(half8*)(WaT + ((size_t)kk4 * HDIM + n) * 8) = v;
}

// ---------------------------------------------------------------------------
// Recurrence. Roles static: bg = bid&7 (chain), ug = bid>>3 (0..7).
// Batches bg*8..+7, units ug*64..+63. Wave w (0..7): units u0=ug*64+w*8..+7,
// split as tile0 = u0..u0+3, tile1 = u0+4..u0+7. MFMA M rows [unit][gate];
// N lanes col 0..15 carry batch (col&7) (cols 8..15 duplicate, discarded).
// h(t) stores into sentinel-poisoned hs are self-announcing; gather = poll
// (all 8 waves, one batch-row each).
// ---------------------------------------------------------------------------
__global__ __launch_bounds__(512, 1) void k_lstm(
    const float* __restrict__ Whh, const float* __restrict__ Wih,
    const float* __restrict__ bih, const float* __restrict__ bhh,
    const f16_t* __restrict__ xT, f16_t* __restrict__ hs) {
  const int tid = threadIdx.x;
  const int w = tid >> 6;                  // wave 0..7
  const int L = tid & 63;
  const int q = L >> 4, col = L & 15;
  const int bid = blockIdx.x;              // 0..63
  const int bg = bid & 7;                  // chain / batch group
  const int ug = bid >> 3;                 // 0..7 unit group

  const int u0 = ug * 64 + w * 8;          // 8 units per wave
  const int b8 = col & 7;                  // chain-local batch
  const int bglob = bg * 8 + b8;           // global batch
  const int myu0 = u0 + q;                 // tile0 unit for this lane
  const int myu1 = u0 + 4 + q;             // tile1 unit

  __shared__ __align__(16) f16_t hin[8][520];   // h(t-1): 1040B stride
  __shared__ __align__(16) f16_t hout[8][72];   // block's h(t): 144B stride

  // Persistent A-fragments: A[m=col][k=q*8+j]; m = unit_local*4 + gate.
  const int arow0 = (col & 3) * HDIM + u0 + (col >> 2);
  const int arow1 = arow0 + 4;
  half8 wAh0[16], wAh1[16], wAx0[8], wAx1[8];
#pragma unroll
  for (int kk = 0; kk < 16; ++kk) {
    wAh0[kk] = load_cvt8(&Whh[(size_t)arow0 * HDIM + kk * 32 + q * 8]);
    wAh1[kk] = load_cvt8(&Whh[(size_t)arow1 * HDIM + kk * 32 + q * 8]);
  }
#pragma unroll
  for (int kk = 0; kk < 8; ++kk) {
    wAx0[kk] = load_cvt8(&Wih[(size_t)arow0 * IDIM + kk * 32 + q * 8]);
    wAx1[kk] = load_cvt8(&Wih[(size_t)arow1 * IDIM + kk * 32 + q * 8]);
  }

  float pb0[4], pb1[4];
#pragma unroll
  for (int r = 0; r < 4; ++r) {
    pb0[r] = bih[r * HDIM + myu0] + bhh[r * HDIM + myu0];
    pb1[r] = bih[r * HDIM + myu1] + bhh[r * HDIM + myu1];
  }

  auto xgemm = [&](int t, f32x4& x0, f32x4& x1) {
    x0 = {0.f, 0.f, 0.f, 0.f};
    x1 = {0.f, 0.f, 0.f, 0.f};
#pragma unroll
    for (int kk = 0; kk < 8; ++kk) {
      half8 bf = *(const half8*)(xT +
          (((size_t)(t - 1) * 32 + kk * 4 + q) * 64 + bglob) * 8);
      x0 = MFMA16(wAx0[kk], bf, x0);
      x1 = MFMA16(wAx1[kk], bf, x1);
    }
  };

  float c0 = 0.f, c1 = 0.f;
  f32x4 xacc0, xacc1;
  xgemm(1, xacc0, xacc1);
  for (int t = 1; t <= TLEN; ++t) {
    // ---- gather h(t-1) with data-embedded readiness: wave w polls the full
    //      512-unit row of batch bg*8+w; only stale lanes re-fetch ----
    {
      const f16_t* src = hs + ((size_t)(t - 1) * BATCH + bg * 8 + w) * HDIM
                         + L * 8;          // 16B per lane, 1KB per wave
      f32x4 v = ld16_llc(src);
      int guard = 0;
      for (;;) {
        const bool ok = clean16(v);
        if (__ballot(ok) == ~0ull) break;
        if (!ok) v = ld16_llc(src);        // exec-masked retry
        if (++guard > (1 << 22)) break;    // fail loud, not hung
      }
      *(f32x4*)&hin[w][L * 8] = v;
    }
    __syncthreads();                       // hin complete

    // ---- MFMA: shared B-frags from LDS feed BOTH M-tiles ----
    f32x4 a0 = xacc0, a1 = {0.f, 0.f, 0.f, 0.f};
    f32x4 a2 = xacc1, a3 = {0.f, 0.f, 0.f, 0.f};
#pragma unroll
    for (int kk = 0; kk < 16; kk += 2) {
      half8 b0 = *(const half8*)&hin[b8][kk * 32 + q * 8];
      half8 b1 = *(const half8*)&hin[b8][(kk + 1) * 32 + q * 8];
      a0 = MFMA16(wAh0[kk], b0, a0);
      a2 = MFMA16(wAh1[kk], b0, a2);
      a1 = MFMA16(wAh0[kk + 1], b1, a1);
      a3 = MFMA16(wAh1[kk + 1], b1, a3);
    }
    const f32x4 acc0 = a0 + a1;
    const f32x4 acc1 = a2 + a3;

    {
      const float ig = sigf(acc0[0] + pb0[0]);
      const float fg = sigf(acc0[1] + pb0[1]);
      const float gg = tanh_fast(acc0[2] + pb0[2]);
      const float og = sigf(acc0[3] + pb0[3]);
      c0 = fg * c0 + ig * gg;
      if (col < 8) hout[col][w * 8 + q] = (f16_t)(og * tanh_fast(c0));
    }
    {
      const float ig = sigf(acc1[0] + pb1[0]);
      const float fg = sigf(acc1[1] + pb1[1]);
      const float gg = tanh_fast(acc1[2] + pb1[2]);
      const float og = sigf(acc1[3] + pb1[3]);
      c1 = fg * c1 + ig * gg;
      if (col < 8) hout[col][w * 8 + 4 + q] = (f16_t)(og * tanh_fast(c1));
    }

    __syncthreads();                       // hout ready, hin consumed

    // ---- wave 0: 8 batches x 128B coalesced stores; no drain, no flag ----
    if (w == 0) {
      const int sb = L >> 3, ck = L & 7;   // batch, 16B chunk
      f32x4 v = *(const f32x4*)&hout[sb][ck * 8];
      f16_t* dst = hs + ((size_t)t * BATCH + bg * 8 + sb) * HDIM
                   + ug * 64 + ck * 8;
      asm volatile("global_store_dwordx4 %0, %1, off sc0 sc1"
                   :: "v"(dst), "v"(v) : "memory");
    }

    // x-projection for the NEXT step: overlaps other blocks' compute
    if (t < TLEN) xgemm(t + 1, xacc0, xacc1);
  }
}

// ---------------------------------------------------------------------------
__global__ __launch_bounds__(256) void k_attn(
    const f16_t* __restrict__ hse, const f16_t* __restrict__ WaT,
    const float* __restrict__ battn, f16_t* __restrict__ E) {
  const int w = threadIdx.x >> 6;
  const int L = threadIdx.x & 63;
  const int q = L >> 4, col = L & 15;
  const int m0 = blockIdx.x * 64 + w * 16;   // r rows (r = t*64+b)
  const int n0 = blockIdx.y * 64;            // h cols

  f32x4 acc[4];
#pragma unroll
  for (int nt = 0; nt < 4; ++nt) acc[nt] = {0.f, 0.f, 0.f, 0.f};

#pragma unroll 4
  for (int kk = 0; kk < 16; ++kk) {          // K = 512
    half8 af = *(const half8*)(hse + (size_t)(m0 + col) * HDIM + kk * 32 + q * 8);
#pragma unroll
    for (int nt = 0; nt < 4; ++nt) {
      half8 bf = *(const half8*)(WaT +
          ((size_t)(kk * 4 + q) * HDIM + n0 + nt * 16 + col) * 8);
      acc[nt] = MFMA16(af, bf, acc[nt]);
    }
  }
#pragma unroll
  for (int nt = 0; nt < 4; ++nt) {
    const int h = n0 + nt * 16 + col;
    const float bias = battn[h];
#pragma unroll
    for (int r = 0; r < 4; ++r) {
      const int m = m0 + q * 4 + r;
      E[(size_t)m * HDIM + h] = (f16_t)__expf(tanh_fast(acc[nt][r] + bias));
    }
  }
}

__global__ __launch_bounds__(256) void k_pool(
    const f16_t* __restrict__ E, const f16_t* __restrict__ hse,
    float* __restrict__ pnum, float* __restrict__ pden) {
  const int b = blockIdx.x;
  const int hc = blockIdx.y;
  const int tc = blockIdx.z;
  const int h = hc * 256 + threadIdx.x;
  float num = 0.f, den = 0.f;
#pragma unroll 4
  for (int tt = 0; tt < 256; ++tt) {
    const int t = tc * 256 + tt;
    const size_t idx = ((size_t)t * BATCH + b) * HDIM + h;
    const float e = (float)E[idx];
    const float hv = (float)hse[idx];
    den += e;
    num += e * hv;
  }
  const size_t pi = ((size_t)tc * BATCH + b) * HDIM + h;
  pnum[pi] = num;
  pden[pi] = den;
}

__global__ __launch_bounds__(256) void k_final(
    const float* __restrict__ pnum, const float* __restrict__ pden,
    float* __restrict__ out) {
  const int i = blockIdx.x * 256 + threadIdx.x;   // b*512+h
  float n = 0.f, d = 0.f;
#pragma unroll
  for (int z = 0; z < 4; ++z) {
    n += pnum[(size_t)z * 32768 + i];
    d += pden[(size_t)z * 32768 + i];
  }
  out[i] = n / d;
}

// ---------------------------------------------------------------------------
extern "C" void kernel_launch(void* const* d_in, const int* in_sizes, int n_in,
                              void* d_out, int out_size, void* d_ws, size_t ws_size,
                              hipStream_t stream) {
  const float* x   = (const float*)d_in[0];
  const float* Wih = (const float*)d_in[1];
  const float* Whh = (const float*)d_in[2];
  const float* bih = (const float*)d_in[3];
  const float* bhh = (const float*)d_in[4];
  const float* Wat = (const float*)d_in[5];
  const float* bat = (const float*)d_in[6];
  float* out = (float*)d_out;

  char* ws = (char*)d_ws;
  const size_t REGA_BYTES = (size_t)64 * 1024 * 1024;                        // xT then E
  const size_t HS_BYTES = (size_t)(TLEN + 1) * BATCH * HDIM * sizeof(f16_t); // 67.2MB
  const size_t WAT_BYTES = (size_t)64 * HDIM * 8 * sizeof(f16_t);            // 512KB
  const size_t P_BYTES = (size_t)4 * BATCH * HDIM * sizeof(float);           // 512KB

  f16_t* xT = (f16_t*)ws;
  f16_t* E  = (f16_t*)ws;
  f16_t* hs = (f16_t*)(ws + REGA_BYTES);
  f16_t* WaT = (f16_t*)(ws + REGA_BYTES + HS_BYTES);
  float* pnum = (float*)(ws + REGA_BYTES + HS_BYTES + WAT_BYTES);
  float* pden = (float*)(ws + REGA_BYTES + HS_BYTES + WAT_BYTES + P_BYTES);

  const size_t SLAB = (size_t)BATCH * HDIM * sizeof(f16_t);   // 64KB
  // slab 0 = h(0) = zeros; slabs 1..1024 = 0xFEFE sentinel (re-poison every
  // launch: the sentinel IS the readiness protocol).
  hipMemsetAsync(hs, 0, SLAB, stream);
  hipMemsetAsync((char*)hs + SLAB, 0xFE, (size_t)TLEN * SLAB, stream);

  k_prep_x<<<dim3(TLEN), 256, 0, stream>>>(x, xT);
  k_prep_w<<<dim3(128), 256, 0, stream>>>(Wat, WaT);
  k_lstm<<<dim3(64), 512, 0, stream>>>(Whh, Wih, bih, bhh, xT, hs);

  const f16_t* hse = hs + (size_t)BATCH * HDIM;   // slab 1 == reference hs[0]
  k_attn<<<dim3(1024, 8), 256, 0, stream>>>(hse, WaT, bat, E);
  k_pool<<<dim3(64, 2, 4), 256, 0, stream>>>(E, hse, pnum, pden);
  k_final<<<dim3(128), 256, 0, stream>>>(pnum, pden, out);
}

// Round 11
// 2717.908 us; speedup vs baseline: 1.6191x; 1.2017x over previous
//
#include <hip/hip_runtime.h>
#include <stdint.h>
#include <stddef.h>

// ---------------------------------------------------------------------------
// LSTM (B=64, T=1024, I=256, H=512) + attention pooling on MI355X (gfx950).
//   k_lstm v15: v8 geometry/protocol VERBATIM (128 blocks x 512 thr; 8
//   chains x 16 blocks of 8 batches x 32 units; sentinel-carrying h at
//   device scope; poll == gather; ~100 VGPR).
//   v14 post-mortem: hipcc holds a hard 128-VGPR cap for 512-thr blocks
//   (measured with launch_bounds arg2 = 2, 1, and bare) -> U=64's ~192-VGPR
//   weight set can never be register-resident; LDS fallback needs 192KB >
//   160KB. The traffic lever is compiler-dead.
//   KEY CHANGE vs v8: per-wave DIRECT h stores (early chunk visibility).
//   v8 gated every 64B h-chunk on a block barrier + wave0's staged store
//   (hout LDS round-trip): chunk visibility = slowest wave + barrier +
//   re-read. v15: each wave shfl-transposes its own 4-unit chunk (4 lane
//   reads per batch) into 8 lanes x 8B and stores sc0 sc1 the moment ITS
//   gates finish. Consumers latch per-16B-lane, so partial rows are used
//   immediately -> producer->consumer pipelining at 64B granularity. The
//   second barrier moves up to just after the MFMA hin reads; gates/store/
//   xgemm run barrier-free. hout LDS deleted. Same coherent-write volume,
//   earlier issue.
// ---------------------------------------------------------------------------

typedef _Float16 f16_t;
typedef _Float16 half8 __attribute__((ext_vector_type(8)));
typedef float f32x4 __attribute__((ext_vector_type(4)));
typedef unsigned int uint2_t __attribute__((ext_vector_type(2)));

#define MFMA16(a, b, c) __builtin_amdgcn_mfma_f32_16x16x32_f16((a), (b), (c), 0, 0, 0)

static constexpr int BATCH = 64;
static constexpr int TLEN = 1024;
static constexpr int IDIM = 256;
static constexpr int HDIM = 512;

__device__ __forceinline__ float sigf(float x) { return 1.f / (1.f + __expf(-x)); }
__device__ __forceinline__ float tanh_fast(float x) {
  float e = __expf(2.f * fabsf(x));
  float t = 1.f - 2.f / (e + 1.f);
  return copysignf(t, x);
}
__device__ __forceinline__ half8 load_cvt8(const float* p) {
  f32x4 a = *(const f32x4*)p;
  f32x4 b = *(const f32x4*)(p + 4);
  half8 r;
#pragma unroll
  for (int j = 0; j < 4; ++j) { r[j] = (f16_t)a[j]; r[4 + j] = (f16_t)b[j]; }
  return r;
}

// device-scope (sc0 sc1) 16B load with completion wait: IC is the coherence
// point across XCDs -- the path v4/v6/v8 validated.
__device__ __forceinline__ f32x4 ld16_llc(const f16_t* p) {
  f32x4 v;
  asm volatile("global_load_dwordx4 %0, %1, off sc0 sc1\n\ts_waitcnt vmcnt(0)"
               : "=&v"(v) : "v"(p) : "memory");
  return v;
}

// true iff none of the 8 f16 lanes equals the 0xFEFE sentinel
__device__ __forceinline__ bool clean16(const f32x4& v) {
  const unsigned* u = (const unsigned*)&v;
  bool ok = true;
#pragma unroll
  for (int i = 0; i < 4; ++i) {
    ok = ok && ((u[i] & 0xFFFFu) != 0xFEFEu);
    ok = ok && ((u[i] >> 16) != 0xFEFEu);
  }
  return ok;
}

// ---------------------------------------------------------------------------
__global__ __launch_bounds__(256) void k_prep_x(const float* __restrict__ x,
                                                f16_t* __restrict__ xT) {
  __shared__ f16_t sx[64][IDIM + 8];
  const int t = blockIdx.x;
  const int tid = threadIdx.x;
#pragma unroll 4
  for (int b = 0; b < 64; ++b)
    sx[b][tid] = (f16_t)x[((size_t)b * TLEN + t) * IDIM + tid];
  __syncthreads();
#pragma unroll
  for (int it = 0; it < 8; ++it) {
    const int c = it * 256 + tid;      // c = kk4*64 + b
    const int b = c & 63, kk4 = c >> 6;
    half8 v = *(const half8*)&sx[b][kk4 * 8];
    *(half8*)(xT + (((size_t)t * 32 + kk4) * 64 + b) * 8) = v;
  }
}

__global__ __launch_bounds__(256) void k_prep_w(const float* __restrict__ Wa,
                                                f16_t* __restrict__ WaT) {
  const int id = blockIdx.x * 256 + threadIdx.x;   // 0..32767
  const int n = id & 511, kk4 = id >> 9;
  half8 v = load_cvt8(&Wa[(size_t)n * HDIM + kk4 * 8]);
  *(half8*)(WaT + ((size_t)kk4 * HDIM + n) * 8) = v;
}

// ---------------------------------------------------------------------------
// Recurrence. Roles static: bg = bid&7 (chain), ug = bid>>3 (rank 0..15).
// Batches bg*8..+7, units ug*32..+31. Wave w (0..7): units u0=ug*32+w*4..+3.
// MFMA M rows [unit][gate]; N lanes col 0..15 carry batch (col&7) (cols
// 8..15 duplicate, discarded on store). h(t) stores into sentinel-poisoned
// hs are self-announcing; gather = poll. Each wave stores its OWN 4-unit
// chunk (shfl-packed, 8 lanes x 8B) as soon as its gates finish.
// ---------------------------------------------------------------------------
__global__ __launch_bounds__(512, 2) void k_lstm(
    const float* __restrict__ Whh, const float* __restrict__ Wih,
    const float* __restrict__ bih, const float* __restrict__ bhh,
    const f16_t* __restrict__ xT, f16_t* __restrict__ hs) {
  const int tid = threadIdx.x;
  const int w = tid >> 6;                  // wave 0..7
  const int L = tid & 63;
  const int q = L >> 4, col = L & 15;
  const int bid = blockIdx.x;
  const int bg = bid & 7;                  // chain / batch group
  const int ug = bid >> 3;                 // 0..15 unit group

  const int u0 = ug * 32 + w * 4;
  const int b8 = col & 7;                  // chain-local batch
  const int bglob = bg * 8 + b8;           // global batch
  const int myu = u0 + q;

  __shared__ __align__(16) f16_t hin[8][520];   // h(t-1): 1040B stride

  // Persistent A-fragments: A[m=col][k=q*8+j]; m = unit_local*4 + gate.
  const int arow = (col & 3) * HDIM + u0 + (col >> 2);
  half8 wAh[16], wAx[8];
#pragma unroll
  for (int kk = 0; kk < 16; ++kk)
    wAh[kk] = load_cvt8(&Whh[(size_t)arow * HDIM + kk * 32 + q * 8]);
#pragma unroll
  for (int kk = 0; kk < 8; ++kk)
    wAx[kk] = load_cvt8(&Wih[(size_t)arow * IDIM + kk * 32 + q * 8]);

  float pb[4];
#pragma unroll
  for (int r = 0; r < 4; ++r) pb[r] = bih[r * HDIM + myu] + bhh[r * HDIM + myu];

  auto xgemm = [&](int t) {
    f32x4 a = {0.f, 0.f, 0.f, 0.f};
#pragma unroll
    for (int kk = 0; kk < 8; ++kk) {
      half8 bf = *(const half8*)(xT +
          (((size_t)(t - 1) * 32 + kk * 4 + q) * 64 + bglob) * 8);
      a = MFMA16(wAx[kk], bf, a);
    }
    return a;
  };

  float c = 0.f;
  f32x4 xacc = xgemm(1);
  for (int t = 1; t <= TLEN; ++t) {
    // ---- gather h(t-1) with data-embedded readiness: wave w polls the full
    //      512-unit row of batch bg*8+w; only stale lanes re-fetch ----
    {
      const f16_t* src = hs + ((size_t)(t - 1) * BATCH + bg * 8 + w) * HDIM
                         + L * 8;          // 16B per lane, 1KB per wave
      f32x4 v = ld16_llc(src);
      int guard = 0;
      for (;;) {
        const bool ok = clean16(v);
        if (__ballot(ok) == ~0ull) break;
        if (!ok) v = ld16_llc(src);        // exec-masked retry
        if (++guard > (1 << 22)) break;    // fail loud, not hung
      }
      *(f32x4*)&hin[w][L * 8] = v;
    }
    __syncthreads();                       // hin complete

    // ---- MFMA: B-frags broadcast-read from LDS, dual accumulators ----
    f32x4 a0 = xacc, a1 = {0.f, 0.f, 0.f, 0.f};
#pragma unroll
    for (int kk = 0; kk < 16; kk += 2) {
      half8 b0 = *(const half8*)&hin[b8][kk * 32 + q * 8];
      half8 b1 = *(const half8*)&hin[b8][(kk + 1) * 32 + q * 8];
      a0 = MFMA16(wAh[kk], b0, a0);
      a1 = MFMA16(wAh[kk + 1], b1, a1);
    }
    __syncthreads();                       // hin consumed -- gates/store/xgemm
                                           // below are barrier-free
    const f32x4 acc = a0 + a1;

    const float ig = sigf(acc[0] + pb[0]);
    const float fg = sigf(acc[1] + pb[1]);
    const float gg = tanh_fast(acc[2] + pb[2]);
    const float og = sigf(acc[3] + pb[3]);
    c = fg * c + ig * gg;
    const f16_t hval = (f16_t)(og * tanh_fast(c));

    // ---- per-wave direct store: shfl-transpose 4 units x 8 batches into
    //      8 lanes x 8B, store sc0 sc1 immediately (chunk visible ASAP) ----
    {
      const unsigned hu = (unsigned)__builtin_bit_cast(unsigned short, hval);
      const int tcol = L & 15;             // target batch for this lane
      const unsigned g0 = (unsigned)__shfl((int)hu, tcol);        // unit +0
      const unsigned g1 = (unsigned)__shfl((int)hu, 16 + tcol);   // unit +1
      const unsigned g2 = (unsigned)__shfl((int)hu, 32 + tcol);   // unit +2
      const unsigned g3 = (unsigned)__shfl((int)hu, 48 + tcol);   // unit +3
      if (L < 8) {                         // one lane per batch row
        uint2_t pk;
        pk[0] = (g0 & 0xFFFFu) | (g1 << 16);
        pk[1] = (g2 & 0xFFFFu) | (g3 << 16);
        f16_t* dst = hs + ((size_t)t * BATCH + bg * 8 + L) * HDIM + u0;
        asm volatile("global_store_dwordx2 %0, %1, off sc0 sc1"
                     :: "v"(dst), "v"(pk) : "memory");
      }
    }

    // x-projection for the NEXT step: overlaps other blocks' compute
    if (t < TLEN) xacc = xgemm(t + 1);
  }
}

// ---------------------------------------------------------------------------
__global__ __launch_bounds__(256) void k_attn(
    const f16_t* __restrict__ hse, const f16_t* __restrict__ WaT,
    const float* __restrict__ battn, f16_t* __restrict__ E) {
  const int w = threadIdx.x >> 6;
  const int L = threadIdx.x & 63;
  const int q = L >> 4, col = L & 15;
  const int m0 = blockIdx.x * 64 + w * 16;   // r rows (r = t*64+b)
  const int n0 = blockIdx.y * 64;            // h cols

  f32x4 acc[4];
#pragma unroll
  for (int nt = 0; nt < 4; ++nt) acc[nt] = {0.f, 0.f, 0.f, 0.f};

#pragma unroll 4
  for (int kk = 0; kk < 16; ++kk) {          // K = 512
    half8 af = *(const half8*)(hse + (size_t)(m0 + col) * HDIM + kk * 32 + q * 8);
#pragma unroll
    for (int nt = 0; nt < 4; ++nt) {
      half8 bf = *(const half8*)(WaT +
          ((size_t)(kk * 4 + q) * HDIM + n0 + nt * 16 + col) * 8);
      acc[nt] = MFMA16(af, bf, acc[nt]);
    }
  }
#pragma unroll
  for (int nt = 0; nt < 4; ++nt) {
    const int h = n0 + nt * 16 + col;
    const float bias = battn[h];
#pragma unroll
    for (int r = 0; r < 4; ++r) {
      const int m = m0 + q * 4 + r;
      E[(size_t)m * HDIM + h] = (f16_t)__expf(tanh_fast(acc[nt][r] + bias));
    }
  }
}

__global__ __launch_bounds__(256) void k_pool(
    const f16_t* __restrict__ E, const f16_t* __restrict__ hse,
    float* __restrict__ pnum, float* __restrict__ pden) {
  const int b = blockIdx.x;
  const int hc = blockIdx.y;
  const int tc = blockIdx.z;
  const int h = hc * 256 + threadIdx.x;
  float num = 0.f, den = 0.f;
#pragma unroll 4
  for (int tt = 0; tt < 256; ++tt) {
    const int t = tc * 256 + tt;
    const size_t idx = ((size_t)t * BATCH + b) * HDIM + h;
    const float e = (float)E[idx];
    const float hv = (float)hse[idx];
    den += e;
    num += e * hv;
  }
  const size_t pi = ((size_t)tc * BATCH + b) * HDIM + h;
  pnum[pi] = num;
  pden[pi] = den;
}

__global__ __launch_bounds__(256) void k_final(
    const float* __restrict__ pnum, const float* __restrict__ pden,
    float* __restrict__ out) {
  const int i = blockIdx.x * 256 + threadIdx.x;   // b*512+h
  float n = 0.f, d = 0.f;
#pragma unroll
  for (int z = 0; z < 4; ++z) {
    n += pnum[(size_t)z * 32768 + i];
    d += pden[(size_t)z * 32768 + i];
  }
  out[i] = n / d;
}

// ---------------------------------------------------------------------------
extern "C" void kernel_launch(void* const* d_in, const int* in_sizes, int n_in,
                              void* d_out, int out_size, void* d_ws, size_t ws_size,
                              hipStream_t stream) {
  const float* x   = (const float*)d_in[0];
  const float* Wih = (const float*)d_in[1];
  const float* Whh = (const float*)d_in[2];
  const float* bih = (const float*)d_in[3];
  const float* bhh = (const float*)d_in[4];
  const float* Wat = (const float*)d_in[5];
  const float* bat = (const float*)d_in[6];
  float* out = (float*)d_out;

  char* ws = (char*)d_ws;
  const size_t REGA_BYTES = (size_t)64 * 1024 * 1024;                        // xT then E
  const size_t HS_BYTES = (size_t)(TLEN + 1) * BATCH * HDIM * sizeof(f16_t); // 67.2MB
  const size_t WAT_BYTES = (size_t)64 * HDIM * 8 * sizeof(f16_t);            // 512KB
  const size_t P_BYTES = (size_t)4 * BATCH * HDIM * sizeof(float);           // 512KB

  f16_t* xT = (f16_t*)ws;
  f16_t* E  = (f16_t*)ws;
  f16_t* hs = (f16_t*)(ws + REGA_BYTES);
  f16_t* WaT = (f16_t*)(ws + REGA_BYTES + HS_BYTES);
  float* pnum = (float*)(ws + REGA_BYTES + HS_BYTES + WAT_BYTES);
  float* pden = (float*)(ws + REGA_BYTES + HS_BYTES + WAT_BYTES + P_BYTES);

  const size_t SLAB = (size_t)BATCH * HDIM * sizeof(f16_t);   // 64KB
  // slab 0 = h(0) = zeros; slabs 1..1024 = 0xFEFE sentinel (re-poison every
  // launch: the sentinel IS the readiness protocol).
  hipMemsetAsync(hs, 0, SLAB, stream);
  hipMemsetAsync((char*)hs + SLAB, 0xFE, (size_t)TLEN * SLAB, stream);

  k_prep_x<<<dim3(TLEN), 256, 0, stream>>>(x, xT);
  k_prep_w<<<dim3(128), 256, 0, stream>>>(Wat, WaT);
  k_lstm<<<dim3(128), 512, 0, stream>>>(Whh, Wih, bih, bhh, xT, hs);

  const f16_t* hse = hs + (size_t)BATCH * HDIM;   // slab 1 == reference hs[0]
  k_attn<<<dim3(1024, 8), 256, 0, stream>>>(hse, WaT, bat, E);
  k_pool<<<dim3(64, 2, 4), 256, 0, stream>>>(E, hse, pnum, pden);
  k_final<<<dim3(128), 256, 0, stream>>>(pnum, pden, out);
}